// Round 8
// baseline (259.555 us; speedup 1.0000x reference)
//
#include <hip/hip_runtime.h>

typedef __bf16 bf16x8 __attribute__((ext_vector_type(8)));
typedef __bf16 bf16x4 __attribute__((ext_vector_type(4)));
typedef __bf16 bf16x2 __attribute__((ext_vector_type(2)));
typedef float  f32x4  __attribute__((ext_vector_type(4)));
typedef float  f32x16 __attribute__((ext_vector_type(16)));
typedef int    i32x4  __attribute__((ext_vector_type(4)));

#define MFMA16 __builtin_amdgcn_mfma_f32_16x16x32_bf16
#define MFMA32 __builtin_amdgcn_mfma_f32_32x32x16_bf16

static constexpr int BATCH = 4;
static constexpr int SEQ   = 4096;
static constexpr int CDIM  = 128;
static constexpr int HDIM  = 64;
static constexpr float FIXMAX = 16.0f;   // log2-domain safe upper bound for scores

union FB2  { bf16x2 h; int i; };
union I4B8 { i32x4 i; bf16x8 b; };

// Load 8 contiguous fp32 and convert to bf16x8
__device__ inline bf16x8 load8f_cvt(const float* __restrict__ p) {
    f32x4 a = *reinterpret_cast<const f32x4*>(p);
    f32x4 b = *reinterpret_cast<const f32x4*>(p + 4);
    bf16x8 r;
    r[0] = (__bf16)a[0]; r[1] = (__bf16)a[1]; r[2] = (__bf16)a[2]; r[3] = (__bf16)a[3];
    r[4] = (__bf16)b[0]; r[5] = (__bf16)b[1]; r[6] = (__bf16)b[2]; r[7] = (__bf16)b[3];
    return r;
}

// ---------------------------------------------------------------------------
// Fragment-swizzled layouts (elements, bf16):
//   Q/K: Xswz[(KT*4 + kc)*512 + (h*32 + row)*8 + j] = X[KT*32+row][kc*16 + h*8 + j]
//   V:   Vswz[(KT*8 + ct*2 + kc2)*512 + (h*32 + c_local)*8 + j]
//          = V^T[ct*32+c_local][KT*32 + kc2*16 + h*8 + j]
// A wave's MFMA A/B fragment for a chunk is the contiguous 1KB at lane*16.
// ---------------------------------------------------------------------------

// ---------------------------------------------------------------------------
// Fused projections, 1024 blocks (unchanged — verified).
// ---------------------------------------------------------------------------
__global__ __launch_bounds__(256) void proj_all_kernel(
    const float* __restrict__ x, const float* __restrict__ y,
    const float* __restrict__ Wq, const float* __restrict__ Wk,
    const float* __restrict__ Wv,
    __bf16* __restrict__ Qw, __bf16* __restrict__ Kw, __bf16* __restrict__ Vtw,
    float qscale)
{
    __shared__ __bf16 Wt[64][136];    // transposed weight slice: Wt[cout][cin]
    __shared__ __bf16 Vtile[64][72];  // V transpose tile [c_local][key_local]

    const int job = blockIdx.x >> 8;
    const int bx  = blockIdx.x & 255;
    const int t    = threadIdx.x;
    const int lane = t & 63;
    const int w    = t >> 6;
    const int m    = lane & 15;
    const int quad = lane >> 4;

    if (job <= 1) {
        const float* X    = job ? y  : x;
        const float* W    = job ? Wk : Wq;
        __bf16*      outp = job ? Kw : Qw;
        const float scale = job ? 1.0f : qscale;

        #pragma unroll
        for (int pass = 0; pass < 4; ++pass) {
            int flat = pass * 2048 + t * 8;
            int cin  = flat >> 6;
            int h0   = flat & 63;
            bf16x8 v = load8f_cvt(W + flat);
            #pragma unroll
            for (int j = 0; j < 8; ++j) Wt[h0 + j][cin] = v[j];
        }
        __syncthreads();

        const int row0 = bx * 64 + w * 16;
        bf16x8 af[4];
        #pragma unroll
        for (int kc = 0; kc < 4; ++kc)
            af[kc] = load8f_cvt(X + (long)(row0 + m) * 128 + kc * 32 + quad * 8);

        #pragma unroll
        for (int tn = 0; tn < 4; ++tn) {
            f32x4 acc = {0.f, 0.f, 0.f, 0.f};
            #pragma unroll
            for (int kc = 0; kc < 4; ++kc) {
                bf16x8 bfrag = *reinterpret_cast<const bf16x8*>(&Wt[tn * 16 + m][kc * 32 + quad * 8]);
                acc = MFMA16(af[kc], bfrag, acc, 0, 0, 0);
            }
            #pragma unroll
            for (int r = 0; r < 4; ++r) {
                int  kg   = row0 + quad * 4 + r;   // global row (incl. batch)
                long addr = ((long)(kg >> 5) * 4 + tn) * 512
                          + ((m >> 3) * 32 + (kg & 31)) * 8 + (m & 7);
                outp[addr] = (__bf16)(acc[r] * scale);
            }
        }
    } else {
        const int cob = (job - 2) * 64;   // cout base
        const int ct0 = (job - 2) * 2;    // 32-col group base

        // stage Wv[:, cob..cob+63] transposed
        #pragma unroll
        for (int pass = 0; pass < 4; ++pass) {
            int flat = pass * 2048 + t * 8;
            int cin  = flat >> 6;
            int co0  = flat & 63;
            bf16x8 v = load8f_cvt(Wv + cin * 128 + cob + co0);
            #pragma unroll
            for (int j = 0; j < 8; ++j) Wt[co0 + j][cin] = v[j];
        }
        __syncthreads();

        const int row0 = bx * 64 + w * 16;   // key rows
        bf16x8 af[4];
        #pragma unroll
        for (int kc = 0; kc < 4; ++kc)
            af[kc] = load8f_cvt(y + (long)(row0 + m) * 128 + kc * 32 + quad * 8);

        #pragma unroll
        for (int tn = 0; tn < 4; ++tn) {
            f32x4 acc = {0.f, 0.f, 0.f, 0.f};
            #pragma unroll
            for (int kc = 0; kc < 4; ++kc) {
                bf16x8 bfrag = *reinterpret_cast<const bf16x8*>(&Wt[tn * 16 + m][kc * 32 + quad * 8]);
                acc = MFMA16(af[kc], bfrag, acc, 0, 0, 0);
            }
            bf16x4 pk;
            #pragma unroll
            for (int r = 0; r < 4; ++r) pk[r] = (__bf16)acc[r];
            *reinterpret_cast<bf16x4*>(&Vtile[tn * 16 + m][w * 16 + quad * 4]) = pk;
        }
        __syncthreads();

        // fragment-ordered coalesced store of the 64key x 64c tile
        #pragma unroll
        for (int pp = 0; pp < 2; ++pp) {
            int i       = pp * 256 + t;
            int c_local = i & 31;
            int hh      = (i >> 5) & 1;
            int kc2     = (i >> 6) & 1;
            int ct_l    = (i >> 7) & 1;
            int kt_l    = i >> 8;
            bf16x8 v = *reinterpret_cast<const bf16x8*>(
                &Vtile[ct_l * 32 + c_local][kt_l * 32 + kc2 * 16 + hh * 8]);
            long dst = ((long)(bx * 2 + kt_l) * 8 + (ct0 + ct_l) * 2 + kc2) * 512
                     + (hh * 32 + c_local) * 8;
            *reinterpret_cast<bf16x8*>(Vtw + dst) = v;
        }
    }
}

// ---------------------------------------------------------------------------
// One flash step for 32 keys: S^T MFMA + fixed-max softmax + in-register
// P transpose + PV MFMA. V frags passed in (loaded early at iter top).
// ---------------------------------------------------------------------------
__device__ __forceinline__ void attn_step(
    const bf16x8 (&kf)[4], const bf16x8 (&vf)[8], const bf16x8 (&qf)[4],
    f32x16 (&o_acc)[4], float& l_a, float& l_b, int h)
{
    f32x16 s;
    #pragma unroll
    for (int i = 0; i < 16; ++i) s[i] = -FIXMAX;
    #pragma unroll
    for (int kc = 0; kc < 4; ++kc)
        s = MFMA32(kf[kc], qf[kc], s, 0, 0, 0);

    int Dw[8];
    #pragma unroll
    for (int r2 = 0; r2 < 8; ++r2) {
        float p0 = __builtin_amdgcn_exp2f(s[2 * r2]);
        float p1 = __builtin_amdgcn_exp2f(s[2 * r2 + 1]);
        l_a += p0; l_b += p1;
        FB2 u; u.h[0] = (__bf16)p0; u.h[1] = (__bf16)p1;
        Dw[r2] = u.i;
    }

    #pragma unroll
    for (int kc2 = 0; kc2 < 2; ++kc2) {
        int a0 = Dw[4 * kc2 + 0], a1 = Dw[4 * kc2 + 1];
        int a2 = Dw[4 * kc2 + 2], a3 = Dw[4 * kc2 + 3];
        int r0 = __shfl_xor(a0, 32, 64);
        int r1 = __shfl_xor(a1, 32, 64);
        int r2 = __shfl_xor(a2, 32, 64);
        int r3 = __shfl_xor(a3, 32, 64);
        I4B8 pb;
        pb.i[0] = h ? r2 : a0;
        pb.i[1] = h ? r3 : a1;
        pb.i[2] = h ? a2 : r0;
        pb.i[3] = h ? a3 : r1;
        #pragma unroll
        for (int ct = 0; ct < 4; ++ct)
            o_acc[ct] = MFMA32(vf[ct * 2 + kc2], pb.b, o_acc[ct], 0, 0, 0);
    }
}

// ---------------------------------------------------------------------------
// Flash attention, 8-way key split for occupancy.
// Grid 512 = 4 batches x 128 q-tiles of 32 rows. Block = 512 thr = 8 waves;
// wave g covers keys [g*512,(g+1)*512), 16 iters of 32 keys. 2 blocks/CU,
// 4 waves/SIMD (launch_bounds caps regs at the 128 cliff). K frags register-
// double-buffered; V frags loaded at iter top (consumed ~330 cyc later).
// Barrier-free K-loop; 3-round LDS merge tree in the epilogue.
// ---------------------------------------------------------------------------
__global__ __launch_bounds__(512, 4) void attn_kernel(
    const __bf16* __restrict__ Qs, const __bf16* __restrict__ Ks,
    const __bf16* __restrict__ Vs, float* __restrict__ out)
{
    __shared__ float mbuf[4][64][66];   // merge tree buffers (epilogue only)

    const int t    = threadIdx.x;
    const int lane = t & 63;
    const int g    = t >> 6;       // key-group 0..7
    const int qc   = lane & 31;    // q column
    const int h    = lane >> 5;

    const int bx  = blockIdx.x;
    const int n   = bx >> 7;       // batch (blocks grouped by batch for L2)
    const int qtl = bx & 127;      // 32-row q-tile within batch

    // Q B-frags: contiguous 1KB per chunk
    const long QT = (long)n * 128 + qtl;
    bf16x8 qf[4];
    #pragma unroll
    for (int kc = 0; kc < 4; ++kc)
        qf[kc] = *reinterpret_cast<const bf16x8*>(Qs + (QT * 4 + kc) * 512 + lane * 8);

    // fragment base pointers for this wave's key stream (KT = n*128 + g*16 + kt)
    const __bf16* kb = Ks + ((long)n * 128 + g * 16) * 2048 + lane * 8;
    const __bf16* vb = Vs + ((long)n * 128 + g * 16) * 4096 + lane * 8;

    f32x16 o_acc[4];
    #pragma unroll
    for (int ct = 0; ct < 4; ++ct)
        #pragma unroll
        for (int i = 0; i < 16; ++i) o_acc[ct][i] = 0.f;
    float l_a = 0.f, l_b = 0.f;

    bf16x8 kf0[4], kf1[4], vf[8];

    // prologue: K frags for iter 0
    #pragma unroll
    for (int kc = 0; kc < 4; ++kc)
        kf0[kc] = *reinterpret_cast<const bf16x8*>(kb + kc * 512);

    for (int kt = 0; kt < 16; kt += 2) {
        // V frags for kt (issued early; consumed after S+softmax)
        {
            const __bf16* vp = vb + (long)kt * 4096;
            #pragma unroll
            for (int c = 0; c < 8; ++c)
                vf[c] = *reinterpret_cast<const bf16x8*>(vp + c * 512);
            const __bf16* kp = kb + (long)(kt + 1) * 2048;
            #pragma unroll
            for (int kc = 0; kc < 4; ++kc)
                kf1[kc] = *reinterpret_cast<const bf16x8*>(kp + kc * 512);
        }
        attn_step(kf0, vf, qf, o_acc, l_a, l_b, h);

        // V frags for kt+1; K frags for kt+2
        {
            const __bf16* vp = vb + (long)(kt + 1) * 4096;
            #pragma unroll
            for (int c = 0; c < 8; ++c)
                vf[c] = *reinterpret_cast<const bf16x8*>(vp + c * 512);
            if (kt < 14) {
                const __bf16* kp = kb + (long)(kt + 2) * 2048;
                #pragma unroll
                for (int kc = 0; kc < 4; ++kc)
                    kf0[kc] = *reinterpret_cast<const bf16x8*>(kp + kc * 512);
            }
        }
        attn_step(kf1, vf, qf, o_acc, l_a, l_b, h);
    }

    float l_run = l_a + l_b;

    // ---- 3-round LDS merge tree over the 8 key-groups (pure sums) ----
    // Round 1: 4..7 -> 0..3
    if (g >= 4) {
        float* dst = &mbuf[g - 4][lane][0];
        #pragma unroll
        for (int ct = 0; ct < 4; ++ct)
            #pragma unroll
            for (int i = 0; i < 16; ++i) dst[ct * 16 + i] = o_acc[ct][i];
        dst[64] = l_run;
    }
    __syncthreads();
    if (g < 4) {
        const float* src = &mbuf[g][lane][0];
        #pragma unroll
        for (int ct = 0; ct < 4; ++ct)
            #pragma unroll
            for (int i = 0; i < 16; ++i) o_acc[ct][i] += src[ct * 16 + i];
        l_run += src[64];
    }
    __syncthreads();
    // Round 2: 2..3 -> 0..1
    if (g == 2 || g == 3) {
        float* dst = &mbuf[g - 2][lane][0];
        #pragma unroll
        for (int ct = 0; ct < 4; ++ct)
            #pragma unroll
            for (int i = 0; i < 16; ++i) dst[ct * 16 + i] = o_acc[ct][i];
        dst[64] = l_run;
    }
    __syncthreads();
    if (g < 2) {
        const float* src = &mbuf[g][lane][0];
        #pragma unroll
        for (int ct = 0; ct < 4; ++ct)
            #pragma unroll
            for (int i = 0; i < 16; ++i) o_acc[ct][i] += src[ct * 16 + i];
        l_run += src[64];
    }
    __syncthreads();
    // Round 3: 1 -> 0
    if (g == 1) {
        float* dst = &mbuf[0][lane][0];
        #pragma unroll
        for (int ct = 0; ct < 4; ++ct)
            #pragma unroll
            for (int i = 0; i < 16; ++i) dst[ct * 16 + i] = o_acc[ct][i];
        dst[64] = l_run;
    }
    __syncthreads();

    if (g == 0) {
        const float* src = &mbuf[0][lane][0];
        #pragma unroll
        for (int ct = 0; ct < 4; ++ct)
            #pragma unroll
            for (int i = 0; i < 16; ++i) o_acc[ct][i] += src[ct * 16 + i];
        l_run += src[64];

        l_run += __shfl_xor(l_run, 32, 64);   // cross-half key sum
        const float inv = 1.0f / l_run;
        const long row = (long)n * SEQ + qtl * 32 + qc;
        #pragma unroll
        for (int ct = 0; ct < 4; ++ct)
            #pragma unroll
            for (int rg = 0; rg < 4; ++rg) {
                f32x4 o;
                #pragma unroll
                for (int i = 0; i < 4; ++i) o[i] = o_acc[ct][rg * 4 + i] * inv;
                *reinterpret_cast<f32x4*>(out + row * CDIM + ct * 32 + rg * 8 + h * 4) = o;
            }
    }
}

// ---------------------------------------------------------------------------
extern "C" void kernel_launch(void* const* d_in, const int* in_sizes, int n_in,
                              void* d_out, int out_size, void* d_ws, size_t ws_size,
                              hipStream_t stream)
{
    const float* x  = (const float*)d_in[0];  // [4,4096,128] fp32
    const float* y  = (const float*)d_in[1];  // [4,4096,128] fp32
    const float* Wq = (const float*)d_in[2];  // [128,64]     fp32
    const float* Wk = (const float*)d_in[3];  // [128,64]     fp32
    const float* Wv = (const float*)d_in[4];  // [128,128]    fp32
    float* out = (float*)d_out;               // [4,4096,128] fp32

    __bf16* Qw  = (__bf16*)d_ws;                         // swizzled Q, 2 MB
    __bf16* Kw  = Qw + (long)BATCH * SEQ * HDIM;         // swizzled K, 2 MB
    __bf16* Vtw = Kw + (long)BATCH * SEQ * HDIM;         // swizzled V^T, 4 MB

    // scale = H^-0.5 * log2(e), folded into Q before bf16 rounding
    const float qscale = 0.125f * 1.4426950408889634f;

    proj_all_kernel<<<dim3(1024), dim3(256), 0, stream>>>(
        x, y, Wq, Wk, Wv, Qw, Kw, Vtw, qscale);

    attn_kernel<<<dim3(512), dim3(512), 0, stream>>>(Qw, Kw, Vtw, out);
}

// Round 9
// 123.084 us; speedup vs baseline: 2.1088x; 2.1088x over previous
//
#include <hip/hip_runtime.h>

typedef __bf16 bf16x8 __attribute__((ext_vector_type(8)));
typedef __bf16 bf16x4 __attribute__((ext_vector_type(4)));
typedef __bf16 bf16x2 __attribute__((ext_vector_type(2)));
typedef float  f32x4  __attribute__((ext_vector_type(4)));
typedef float  f32x16 __attribute__((ext_vector_type(16)));
typedef int    i32x4  __attribute__((ext_vector_type(4)));

#define MFMA16 __builtin_amdgcn_mfma_f32_16x16x32_bf16
#define MFMA32 __builtin_amdgcn_mfma_f32_32x32x16_bf16

static constexpr int BATCH = 4;
static constexpr int SEQ   = 4096;
static constexpr int CDIM  = 128;
static constexpr int HDIM  = 64;
static constexpr float FIXMAX = 16.0f;   // log2-domain safe upper bound for scores

union FB2  { bf16x2 h; int i; };
union I4B8 { i32x4 i; bf16x8 b; };

// Load 8 contiguous fp32 and convert to bf16x8
__device__ inline bf16x8 load8f_cvt(const float* __restrict__ p) {
    f32x4 a = *reinterpret_cast<const f32x4*>(p);
    f32x4 b = *reinterpret_cast<const f32x4*>(p + 4);
    bf16x8 r;
    r[0] = (__bf16)a[0]; r[1] = (__bf16)a[1]; r[2] = (__bf16)a[2]; r[3] = (__bf16)a[3];
    r[4] = (__bf16)b[0]; r[5] = (__bf16)b[1]; r[6] = (__bf16)b[2]; r[7] = (__bf16)b[3];
    return r;
}

// ---------------------------------------------------------------------------
// Fragment-swizzled layouts (elements, bf16):
//   Q/K: Xswz[(KT*4 + kc)*512 + (h*32 + row)*8 + j] = X[KT*32+row][kc*16 + h*8 + j]
//   V:   Vswz[(KT*8 + ct*2 + kc2)*512 + (h*32 + c_local)*8 + j]
//          = V^T[ct*32+c_local][KT*32 + kc2*16 + h*8 + j]
// A wave's MFMA A/B fragment for a chunk is the contiguous 1KB at lane*16.
// ---------------------------------------------------------------------------

// ---------------------------------------------------------------------------
// Fused projections, 1024 blocks (unchanged — verified).
// ---------------------------------------------------------------------------
__global__ __launch_bounds__(256) void proj_all_kernel(
    const float* __restrict__ x, const float* __restrict__ y,
    const float* __restrict__ Wq, const float* __restrict__ Wk,
    const float* __restrict__ Wv,
    __bf16* __restrict__ Qw, __bf16* __restrict__ Kw, __bf16* __restrict__ Vtw,
    float qscale)
{
    __shared__ __bf16 Wt[64][136];    // transposed weight slice: Wt[cout][cin]
    __shared__ __bf16 Vtile[64][72];  // V transpose tile [c_local][key_local]

    const int job = blockIdx.x >> 8;
    const int bx  = blockIdx.x & 255;
    const int t    = threadIdx.x;
    const int lane = t & 63;
    const int w    = t >> 6;
    const int m    = lane & 15;
    const int quad = lane >> 4;

    if (job <= 1) {
        const float* X    = job ? y  : x;
        const float* W    = job ? Wk : Wq;
        __bf16*      outp = job ? Kw : Qw;
        const float scale = job ? 1.0f : qscale;

        #pragma unroll
        for (int pass = 0; pass < 4; ++pass) {
            int flat = pass * 2048 + t * 8;
            int cin  = flat >> 6;
            int h0   = flat & 63;
            bf16x8 v = load8f_cvt(W + flat);
            #pragma unroll
            for (int j = 0; j < 8; ++j) Wt[h0 + j][cin] = v[j];
        }
        __syncthreads();

        const int row0 = bx * 64 + w * 16;
        bf16x8 af[4];
        #pragma unroll
        for (int kc = 0; kc < 4; ++kc)
            af[kc] = load8f_cvt(X + (long)(row0 + m) * 128 + kc * 32 + quad * 8);

        #pragma unroll
        for (int tn = 0; tn < 4; ++tn) {
            f32x4 acc = {0.f, 0.f, 0.f, 0.f};
            #pragma unroll
            for (int kc = 0; kc < 4; ++kc) {
                bf16x8 bfrag = *reinterpret_cast<const bf16x8*>(&Wt[tn * 16 + m][kc * 32 + quad * 8]);
                acc = MFMA16(af[kc], bfrag, acc, 0, 0, 0);
            }
            #pragma unroll
            for (int r = 0; r < 4; ++r) {
                int  kg   = row0 + quad * 4 + r;   // global row (incl. batch)
                long addr = ((long)(kg >> 5) * 4 + tn) * 512
                          + ((m >> 3) * 32 + (kg & 31)) * 8 + (m & 7);
                outp[addr] = (__bf16)(acc[r] * scale);
            }
        }
    } else {
        const int cob = (job - 2) * 64;   // cout base
        const int ct0 = (job - 2) * 2;    // 32-col group base

        // stage Wv[:, cob..cob+63] transposed
        #pragma unroll
        for (int pass = 0; pass < 4; ++pass) {
            int flat = pass * 2048 + t * 8;
            int cin  = flat >> 6;
            int co0  = flat & 63;
            bf16x8 v = load8f_cvt(Wv + cin * 128 + cob + co0);
            #pragma unroll
            for (int j = 0; j < 8; ++j) Wt[co0 + j][cin] = v[j];
        }
        __syncthreads();

        const int row0 = bx * 64 + w * 16;   // key rows
        bf16x8 af[4];
        #pragma unroll
        for (int kc = 0; kc < 4; ++kc)
            af[kc] = load8f_cvt(y + (long)(row0 + m) * 128 + kc * 32 + quad * 8);

        #pragma unroll
        for (int tn = 0; tn < 4; ++tn) {
            f32x4 acc = {0.f, 0.f, 0.f, 0.f};
            #pragma unroll
            for (int kc = 0; kc < 4; ++kc) {
                bf16x8 bfrag = *reinterpret_cast<const bf16x8*>(&Wt[tn * 16 + m][kc * 32 + quad * 8]);
                acc = MFMA16(af[kc], bfrag, acc, 0, 0, 0);
            }
            bf16x4 pk;
            #pragma unroll
            for (int r = 0; r < 4; ++r) pk[r] = (__bf16)acc[r];
            *reinterpret_cast<bf16x4*>(&Vtile[tn * 16 + m][w * 16 + quad * 4]) = pk;
        }
        __syncthreads();

        // fragment-ordered coalesced store of the 64key x 64c tile
        #pragma unroll
        for (int pp = 0; pp < 2; ++pp) {
            int i       = pp * 256 + t;
            int c_local = i & 31;
            int hh      = (i >> 5) & 1;
            int kc2     = (i >> 6) & 1;
            int ct_l    = (i >> 7) & 1;
            int kt_l    = i >> 8;
            bf16x8 v = *reinterpret_cast<const bf16x8*>(
                &Vtile[ct_l * 32 + c_local][kt_l * 32 + kc2 * 16 + hh * 8]);
            long dst = ((long)(bx * 2 + kt_l) * 8 + (ct0 + ct_l) * 2 + kc2) * 512
                     + (hh * 32 + c_local) * 8;
            *reinterpret_cast<bf16x8*>(Vtw + dst) = v;
        }
    }
}

// ---------------------------------------------------------------------------
// Flash attention, c-split for register fit at 4 waves/SIMD.
// Grid 512 = 4 batches x 128 q-tiles (32 rows). Block = 512 thr = 8 waves =
// 2 c-halves x 4 key-groups. Each wave: 32 q-rows x 64 channels, 1024 keys
// (32 iters of 32). S computed by both c-halves (redundant, +33% MFMA) so
// each wave is self-contained: o_acc 32 + s 16 + qf 16 + kf 16 + vf 16 regs
// ~= 110 < 128 cap => no spills at 2 blocks/CU (16 waves/CU, 4/SIMD).
// Fixed-max softmax; in-register P transpose; 2-round LDS merge epilogue.
// ---------------------------------------------------------------------------
__global__ __launch_bounds__(512, 4) void attn_kernel(
    const __bf16* __restrict__ Qs, const __bf16* __restrict__ Ks,
    const __bf16* __restrict__ Vs, float* __restrict__ out)
{
    __shared__ float mbuf[2][2][64][33];   // [c-half][slot][lane][32 o + l]

    const int t    = threadIdx.x;
    const int lane = t & 63;
    const int w    = t >> 6;       // 0..7
    const int ch   = w & 1;        // c-half: channels [ch*64, ch*64+64)
    const int g    = w >> 1;       // key-group 0..3 (keys [g*1024, +1024))
    const int qc   = lane & 31;    // q column
    const int h    = lane >> 5;

    const int bx  = blockIdx.x;
    const int n   = bx >> 7;       // batch
    const int qtl = bx & 127;      // 32-row q-tile within batch

    // Q B-frags: contiguous 1KB per chunk
    const long QT = (long)n * 128 + qtl;
    bf16x8 qf[4];
    #pragma unroll
    for (int kc = 0; kc < 4; ++kc)
        qf[kc] = *reinterpret_cast<const bf16x8*>(Qs + (QT * 4 + kc) * 512 + lane * 8);

    // key stream bases (KT = n*128 + g*32 + kt)
    const __bf16* kb = Ks + ((long)n * 128 + g * 32) * 2048 + lane * 8;
    const __bf16* vb = Vs + ((long)n * 128 + g * 32) * 4096 + (long)ch * 4 * 512 + lane * 8;

    f32x16 o_acc[2];
    #pragma unroll
    for (int ctl = 0; ctl < 2; ++ctl)
        #pragma unroll
        for (int i = 0; i < 16; ++i) o_acc[ctl][i] = 0.f;
    float l_a = 0.f, l_b = 0.f;

    for (int kt = 0; kt < 32; ++kt) {
        // K frags (shared with the pair wave via L1) and V frags (this c-half)
        bf16x8 kf[4], vf[4];
        const __bf16* kp = kb + (long)kt * 2048;
        const __bf16* vp = vb + (long)kt * 4096;
        #pragma unroll
        for (int kc = 0; kc < 4; ++kc)
            kf[kc] = *reinterpret_cast<const bf16x8*>(kp + kc * 512);
        #pragma unroll
        for (int j = 0; j < 4; ++j)
            vf[j] = *reinterpret_cast<const bf16x8*>(vp + j * 512);

        // S^T = K.Q^T, pre-shifted by -FIXMAX via accumulator init
        f32x16 s;
        #pragma unroll
        for (int i = 0; i < 16; ++i) s[i] = -FIXMAX;
        #pragma unroll
        for (int kc = 0; kc < 4; ++kc)
            s = MFMA32(kf[kc], qf[kc], s, 0, 0, 0);

        // fixed-max softmax: p = exp2(s - FIXMAX); pack bf16 pairs
        int Dw[8];
        #pragma unroll
        for (int r2 = 0; r2 < 8; ++r2) {
            float p0 = __builtin_amdgcn_exp2f(s[2 * r2]);
            float p1 = __builtin_amdgcn_exp2f(s[2 * r2 + 1]);
            l_a += p0; l_b += p1;
            FB2 u; u.h[0] = (__bf16)p0; u.h[1] = (__bf16)p1;
            Dw[r2] = u.i;
        }

        // C-layout -> B-layout in-register; PV over this wave's 64 channels
        #pragma unroll
        for (int kc2 = 0; kc2 < 2; ++kc2) {
            int a0 = Dw[4 * kc2 + 0], a1 = Dw[4 * kc2 + 1];
            int a2 = Dw[4 * kc2 + 2], a3 = Dw[4 * kc2 + 3];
            int r0 = __shfl_xor(a0, 32, 64);
            int r1 = __shfl_xor(a1, 32, 64);
            int r2 = __shfl_xor(a2, 32, 64);
            int r3 = __shfl_xor(a3, 32, 64);
            I4B8 pb;
            pb.i[0] = h ? r2 : a0;
            pb.i[1] = h ? r3 : a1;
            pb.i[2] = h ? a2 : r0;
            pb.i[3] = h ? a3 : r1;
            #pragma unroll
            for (int ctl = 0; ctl < 2; ++ctl)
                o_acc[ctl] = MFMA32(vf[ctl * 2 + kc2], pb.b, o_acc[ctl], 0, 0, 0);
        }
    }

    float l_run = l_a + l_b;

    // ---- 2-round LDS merge tree over the 4 key-groups per c-half ----
    // Round 1: g=2,3 -> slots 0,1
    if (g >= 2) {
        float* dst = &mbuf[ch][g - 2][lane][0];
        #pragma unroll
        for (int ctl = 0; ctl < 2; ++ctl)
            #pragma unroll
            for (int i = 0; i < 16; ++i) dst[ctl * 16 + i] = o_acc[ctl][i];
        dst[32] = l_run;
    }
    __syncthreads();
    if (g < 2) {
        const float* src = &mbuf[ch][g][lane][0];
        #pragma unroll
        for (int ctl = 0; ctl < 2; ++ctl)
            #pragma unroll
            for (int i = 0; i < 16; ++i) o_acc[ctl][i] += src[ctl * 16 + i];
        l_run += src[32];
    }
    __syncthreads();
    // Round 2: g=1 -> slot 0
    if (g == 1) {
        float* dst = &mbuf[ch][0][lane][0];
        #pragma unroll
        for (int ctl = 0; ctl < 2; ++ctl)
            #pragma unroll
            for (int i = 0; i < 16; ++i) dst[ctl * 16 + i] = o_acc[ctl][i];
        dst[32] = l_run;
    }
    __syncthreads();

    if (g == 0) {
        const float* src = &mbuf[ch][0][lane][0];
        #pragma unroll
        for (int ctl = 0; ctl < 2; ++ctl)
            #pragma unroll
            for (int i = 0; i < 16; ++i) o_acc[ctl][i] += src[ctl * 16 + i];
        l_run += src[32];

        l_run += __shfl_xor(l_run, 32, 64);   // cross-half key sum
        const float inv = 1.0f / l_run;
        const long row = (long)n * SEQ + qtl * 32 + qc;
        #pragma unroll
        for (int ctl = 0; ctl < 2; ++ctl)
            #pragma unroll
            for (int rg = 0; rg < 4; ++rg) {
                f32x4 o;
                #pragma unroll
                for (int i = 0; i < 4; ++i) o[i] = o_acc[ctl][rg * 4 + i] * inv;
                *reinterpret_cast<f32x4*>(
                    out + row * CDIM + ch * 64 + ctl * 32 + rg * 8 + h * 4) = o;
            }
    }
}

// ---------------------------------------------------------------------------
extern "C" void kernel_launch(void* const* d_in, const int* in_sizes, int n_in,
                              void* d_out, int out_size, void* d_ws, size_t ws_size,
                              hipStream_t stream)
{
    const float* x  = (const float*)d_in[0];  // [4,4096,128] fp32
    const float* y  = (const float*)d_in[1];  // [4,4096,128] fp32
    const float* Wq = (const float*)d_in[2];  // [128,64]     fp32
    const float* Wk = (const float*)d_in[3];  // [128,64]     fp32
    const float* Wv = (const float*)d_in[4];  // [128,128]    fp32
    float* out = (float*)d_out;               // [4,4096,128] fp32

    __bf16* Qw  = (__bf16*)d_ws;                         // swizzled Q, 2 MB
    __bf16* Kw  = Qw + (long)BATCH * SEQ * HDIM;         // swizzled K, 2 MB
    __bf16* Vtw = Kw + (long)BATCH * SEQ * HDIM;         // swizzled V^T, 4 MB

    // scale = H^-0.5 * log2(e), folded into Q before bf16 rounding
    const float qscale = 0.125f * 1.4426950408889634f;

    proj_all_kernel<<<dim3(1024), dim3(256), 0, stream>>>(
        x, y, Wq, Wk, Wv, Qw, Kw, Vtw, qscale);

    attn_kernel<<<dim3(512), dim3(512), 0, stream>>>(Qw, Kw, Vtw, out);
}

// Round 10
// 119.991 us; speedup vs baseline: 2.1631x; 1.0258x over previous
//
#include <hip/hip_runtime.h>

typedef __bf16 bf16x8 __attribute__((ext_vector_type(8)));
typedef __bf16 bf16x4 __attribute__((ext_vector_type(4)));
typedef __bf16 bf16x2 __attribute__((ext_vector_type(2)));
typedef float  f32x4  __attribute__((ext_vector_type(4)));
typedef float  f32x16 __attribute__((ext_vector_type(16)));
typedef int    i32x4  __attribute__((ext_vector_type(4)));

#define MFMA16 __builtin_amdgcn_mfma_f32_16x16x32_bf16
#define MFMA32 __builtin_amdgcn_mfma_f32_32x32x16_bf16

static constexpr int BATCH = 4;
static constexpr int SEQ   = 4096;
static constexpr int CDIM  = 128;
static constexpr int HDIM  = 64;
static constexpr float FIXMAX = 16.0f;   // log2-domain safe upper bound for scores

union FB2  { bf16x2 h; int i; };
union I4B8 { i32x4 i; bf16x8 b; };

// Load 8 contiguous fp32 and convert to bf16x8
__device__ inline bf16x8 load8f_cvt(const float* __restrict__ p) {
    f32x4 a = *reinterpret_cast<const f32x4*>(p);
    f32x4 b = *reinterpret_cast<const f32x4*>(p + 4);
    bf16x8 r;
    r[0] = (__bf16)a[0]; r[1] = (__bf16)a[1]; r[2] = (__bf16)a[2]; r[3] = (__bf16)a[3];
    r[4] = (__bf16)b[0]; r[5] = (__bf16)b[1]; r[6] = (__bf16)b[2]; r[7] = (__bf16)b[3];
    return r;
}

// ---------------------------------------------------------------------------
// Fragment-swizzled layouts (elements, bf16):
//   Q/K: Xswz[(KT*4 + kc)*512 + (h*32 + row)*8 + j] = X[KT*32+row][kc*16 + h*8 + j]
//   V:   Vswz[(KT*8 + ct*2 + kc2)*512 + (h*32 + c_local)*8 + j]
//          = V^T[ct*32+c_local][KT*32 + kc2*16 + h*8 + j]
// A wave's MFMA A/B fragment for a chunk is the contiguous 1KB at lane*16.
// ---------------------------------------------------------------------------

// ---------------------------------------------------------------------------
// Fused projections, 1024 blocks (unchanged — verified).
// ---------------------------------------------------------------------------
__global__ __launch_bounds__(256) void proj_all_kernel(
    const float* __restrict__ x, const float* __restrict__ y,
    const float* __restrict__ Wq, const float* __restrict__ Wk,
    const float* __restrict__ Wv,
    __bf16* __restrict__ Qw, __bf16* __restrict__ Kw, __bf16* __restrict__ Vtw,
    float qscale)
{
    __shared__ __bf16 Wt[64][136];    // transposed weight slice: Wt[cout][cin]
    __shared__ __bf16 Vtile[64][72];  // V transpose tile [c_local][key_local]

    const int job = blockIdx.x >> 8;
    const int bx  = blockIdx.x & 255;
    const int t    = threadIdx.x;
    const int lane = t & 63;
    const int w    = t >> 6;
    const int m    = lane & 15;
    const int quad = lane >> 4;

    if (job <= 1) {
        const float* X    = job ? y  : x;
        const float* W    = job ? Wk : Wq;
        __bf16*      outp = job ? Kw : Qw;
        const float scale = job ? 1.0f : qscale;

        #pragma unroll
        for (int pass = 0; pass < 4; ++pass) {
            int flat = pass * 2048 + t * 8;
            int cin  = flat >> 6;
            int h0   = flat & 63;
            bf16x8 v = load8f_cvt(W + flat);
            #pragma unroll
            for (int j = 0; j < 8; ++j) Wt[h0 + j][cin] = v[j];
        }
        __syncthreads();

        const int row0 = bx * 64 + w * 16;
        bf16x8 af[4];
        #pragma unroll
        for (int kc = 0; kc < 4; ++kc)
            af[kc] = load8f_cvt(X + (long)(row0 + m) * 128 + kc * 32 + quad * 8);

        #pragma unroll
        for (int tn = 0; tn < 4; ++tn) {
            f32x4 acc = {0.f, 0.f, 0.f, 0.f};
            #pragma unroll
            for (int kc = 0; kc < 4; ++kc) {
                bf16x8 bfrag = *reinterpret_cast<const bf16x8*>(&Wt[tn * 16 + m][kc * 32 + quad * 8]);
                acc = MFMA16(af[kc], bfrag, acc, 0, 0, 0);
            }
            #pragma unroll
            for (int r = 0; r < 4; ++r) {
                int  kg   = row0 + quad * 4 + r;   // global row (incl. batch)
                long addr = ((long)(kg >> 5) * 4 + tn) * 512
                          + ((m >> 3) * 32 + (kg & 31)) * 8 + (m & 7);
                outp[addr] = (__bf16)(acc[r] * scale);
            }
        }
    } else {
        const int cob = (job - 2) * 64;   // cout base
        const int ct0 = (job - 2) * 2;    // 32-col group base

        // stage Wv[:, cob..cob+63] transposed
        #pragma unroll
        for (int pass = 0; pass < 4; ++pass) {
            int flat = pass * 2048 + t * 8;
            int cin  = flat >> 6;
            int co0  = flat & 63;
            bf16x8 v = load8f_cvt(Wv + cin * 128 + cob + co0);
            #pragma unroll
            for (int j = 0; j < 8; ++j) Wt[co0 + j][cin] = v[j];
        }
        __syncthreads();

        const int row0 = bx * 64 + w * 16;   // key rows
        bf16x8 af[4];
        #pragma unroll
        for (int kc = 0; kc < 4; ++kc)
            af[kc] = load8f_cvt(y + (long)(row0 + m) * 128 + kc * 32 + quad * 8);

        #pragma unroll
        for (int tn = 0; tn < 4; ++tn) {
            f32x4 acc = {0.f, 0.f, 0.f, 0.f};
            #pragma unroll
            for (int kc = 0; kc < 4; ++kc) {
                bf16x8 bfrag = *reinterpret_cast<const bf16x8*>(&Wt[tn * 16 + m][kc * 32 + quad * 8]);
                acc = MFMA16(af[kc], bfrag, acc, 0, 0, 0);
            }
            bf16x4 pk;
            #pragma unroll
            for (int r = 0; r < 4; ++r) pk[r] = (__bf16)acc[r];
            *reinterpret_cast<bf16x4*>(&Vtile[tn * 16 + m][w * 16 + quad * 4]) = pk;
        }
        __syncthreads();

        // fragment-ordered coalesced store of the 64key x 64c tile
        #pragma unroll
        for (int pp = 0; pp < 2; ++pp) {
            int i       = pp * 256 + t;
            int c_local = i & 31;
            int hh      = (i >> 5) & 1;
            int kc2     = (i >> 6) & 1;
            int ct_l    = (i >> 7) & 1;
            int kt_l    = i >> 8;
            bf16x8 v = *reinterpret_cast<const bf16x8*>(
                &Vtile[ct_l * 32 + c_local][kt_l * 32 + kc2 * 16 + hh * 8]);
            long dst = ((long)(bx * 2 + kt_l) * 8 + (ct0 + ct_l) * 2 + kc2) * 512
                     + (hh * 32 + c_local) * 8;
            *reinterpret_cast<bf16x8*>(Vtw + dst) = v;
        }
    }
}

// ---------------------------------------------------------------------------
// Flash attention. Block = 1024 thr = 16 waves = 2 q-subtiles x 2 c-halves x
// 4 key-groups; grid 256 = 4 batches x 64 q-tiles (64 rows) = 1 block/CU,
// 4 waves/SIMD. Wave inner loop identical to round 9 (verified, ~108 regs):
// 32 q-rows x 64 channels x 1024 keys, 32 iters of 32 keys. K streams shared
// by 4 sibling waves, V by 2 (L1 reuse) => unique L2 traffic halves vs r9.
// Fixed-max softmax; in-register P transpose; 2-round LDS merge epilogue.
// ---------------------------------------------------------------------------
__global__ __launch_bounds__(1024, 4) void attn_kernel(
    const __bf16* __restrict__ Qs, const __bf16* __restrict__ Ks,
    const __bf16* __restrict__ Vs, float* __restrict__ out)
{
    __shared__ float mbuf[2][2][2][64][33];  // [qs][ch][slot][lane][32 o + l]

    const int t    = threadIdx.x;
    const int lane = t & 63;
    const int w    = t >> 6;       // 0..15
    const int qs   = w & 1;        // q sub-tile (32 rows)
    const int ch   = (w >> 1) & 1; // c-half: channels [ch*64, ch*64+64)
    const int g    = w >> 2;       // key-group 0..3 (keys [g*1024, +1024))
    const int qc   = lane & 31;    // q column
    const int h    = lane >> 5;

    const int bx  = blockIdx.x;
    const int n   = bx >> 6;       // batch
    const int qtl = bx & 63;       // 64-row q-tile within batch

    // Q B-frags: contiguous 1KB per chunk
    const long QT = (long)n * 128 + qtl * 2 + qs;
    bf16x8 qf[4];
    #pragma unroll
    for (int kc = 0; kc < 4; ++kc)
        qf[kc] = *reinterpret_cast<const bf16x8*>(Qs + (QT * 4 + kc) * 512 + lane * 8);

    // key stream bases (KT = n*128 + g*32 + kt)
    const __bf16* kb = Ks + ((long)n * 128 + g * 32) * 2048 + lane * 8;
    const __bf16* vb = Vs + ((long)n * 128 + g * 32) * 4096 + (long)ch * 4 * 512 + lane * 8;

    f32x16 o_acc[2];
    #pragma unroll
    for (int ctl = 0; ctl < 2; ++ctl)
        #pragma unroll
        for (int i = 0; i < 16; ++i) o_acc[ctl][i] = 0.f;
    float l_a = 0.f, l_b = 0.f;

    for (int kt = 0; kt < 32; ++kt) {
        // K frags (shared with 3 sibling waves via L1) and V frags (this c-half)
        bf16x8 kf[4], vf[4];
        const __bf16* kp = kb + (long)kt * 2048;
        const __bf16* vp = vb + (long)kt * 4096;
        #pragma unroll
        for (int kc = 0; kc < 4; ++kc)
            kf[kc] = *reinterpret_cast<const bf16x8*>(kp + kc * 512);
        #pragma unroll
        for (int j = 0; j < 4; ++j)
            vf[j] = *reinterpret_cast<const bf16x8*>(vp + j * 512);

        // S^T = K.Q^T, pre-shifted by -FIXMAX via accumulator init
        f32x16 s;
        #pragma unroll
        for (int i = 0; i < 16; ++i) s[i] = -FIXMAX;
        #pragma unroll
        for (int kc = 0; kc < 4; ++kc)
            s = MFMA32(kf[kc], qf[kc], s, 0, 0, 0);

        // fixed-max softmax: p = exp2(s - FIXMAX); pack bf16 pairs
        int Dw[8];
        #pragma unroll
        for (int r2 = 0; r2 < 8; ++r2) {
            float p0 = __builtin_amdgcn_exp2f(s[2 * r2]);
            float p1 = __builtin_amdgcn_exp2f(s[2 * r2 + 1]);
            l_a += p0; l_b += p1;
            FB2 u; u.h[0] = (__bf16)p0; u.h[1] = (__bf16)p1;
            Dw[r2] = u.i;
        }

        // C-layout -> B-layout in-register; PV over this wave's 64 channels
        #pragma unroll
        for (int kc2 = 0; kc2 < 2; ++kc2) {
            int a0 = Dw[4 * kc2 + 0], a1 = Dw[4 * kc2 + 1];
            int a2 = Dw[4 * kc2 + 2], a3 = Dw[4 * kc2 + 3];
            int r0 = __shfl_xor(a0, 32, 64);
            int r1 = __shfl_xor(a1, 32, 64);
            int r2 = __shfl_xor(a2, 32, 64);
            int r3 = __shfl_xor(a3, 32, 64);
            I4B8 pb;
            pb.i[0] = h ? r2 : a0;
            pb.i[1] = h ? r3 : a1;
            pb.i[2] = h ? a2 : r0;
            pb.i[3] = h ? a3 : r1;
            #pragma unroll
            for (int ctl = 0; ctl < 2; ++ctl)
                o_acc[ctl] = MFMA32(vf[ctl * 2 + kc2], pb.b, o_acc[ctl], 0, 0, 0);
        }
    }

    float l_run = l_a + l_b;

    // ---- 2-round LDS merge tree over the 4 key-groups per (qs, ch) ----
    // Round 1: g=2,3 -> slots 0,1
    if (g >= 2) {
        float* dst = &mbuf[qs][ch][g - 2][lane][0];
        #pragma unroll
        for (int ctl = 0; ctl < 2; ++ctl)
            #pragma unroll
            for (int i = 0; i < 16; ++i) dst[ctl * 16 + i] = o_acc[ctl][i];
        dst[32] = l_run;
    }
    __syncthreads();
    if (g < 2) {
        const float* src = &mbuf[qs][ch][g][lane][0];
        #pragma unroll
        for (int ctl = 0; ctl < 2; ++ctl)
            #pragma unroll
            for (int i = 0; i < 16; ++i) o_acc[ctl][i] += src[ctl * 16 + i];
        l_run += src[32];
    }
    __syncthreads();
    // Round 2: g=1 -> slot 0
    if (g == 1) {
        float* dst = &mbuf[qs][ch][0][lane][0];
        #pragma unroll
        for (int ctl = 0; ctl < 2; ++ctl)
            #pragma unroll
            for (int i = 0; i < 16; ++i) dst[ctl * 16 + i] = o_acc[ctl][i];
        dst[32] = l_run;
    }
    __syncthreads();

    if (g == 0) {
        const float* src = &mbuf[qs][ch][0][lane][0];
        #pragma unroll
        for (int ctl = 0; ctl < 2; ++ctl)
            #pragma unroll
            for (int i = 0; i < 16; ++i) o_acc[ctl][i] += src[ctl * 16 + i];
        l_run += src[32];

        l_run += __shfl_xor(l_run, 32, 64);   // cross-half key sum
        const float inv = 1.0f / l_run;
        const long row = (long)n * SEQ + qtl * 64 + qs * 32 + qc;
        #pragma unroll
        for (int ctl = 0; ctl < 2; ++ctl)
            #pragma unroll
            for (int rg = 0; rg < 4; ++rg) {
                f32x4 o;
                #pragma unroll
                for (int i = 0; i < 4; ++i) o[i] = o_acc[ctl][rg * 4 + i] * inv;
                *reinterpret_cast<f32x4*>(
                    out + row * CDIM + ch * 64 + ctl * 32 + rg * 8 + h * 4) = o;
            }
    }
}

// ---------------------------------------------------------------------------
extern "C" void kernel_launch(void* const* d_in, const int* in_sizes, int n_in,
                              void* d_out, int out_size, void* d_ws, size_t ws_size,
                              hipStream_t stream)
{
    const float* x  = (const float*)d_in[0];  // [4,4096,128] fp32
    const float* y  = (const float*)d_in[1];  // [4,4096,128] fp32
    const float* Wq = (const float*)d_in[2];  // [128,64]     fp32
    const float* Wk = (const float*)d_in[3];  // [128,64]     fp32
    const float* Wv = (const float*)d_in[4];  // [128,128]    fp32
    float* out = (float*)d_out;               // [4,4096,128] fp32

    __bf16* Qw  = (__bf16*)d_ws;                         // swizzled Q, 2 MB
    __bf16* Kw  = Qw + (long)BATCH * SEQ * HDIM;         // swizzled K, 2 MB
    __bf16* Vtw = Kw + (long)BATCH * SEQ * HDIM;         // swizzled V^T, 4 MB

    // scale = H^-0.5 * log2(e), folded into Q before bf16 rounding
    const float qscale = 0.125f * 1.4426950408889634f;

    proj_all_kernel<<<dim3(1024), dim3(256), 0, stream>>>(
        x, y, Wq, Wk, Wv, Qw, Kw, Vtw, qscale);

    attn_kernel<<<dim3(256), dim3(1024), 0, stream>>>(Qw, Kw, Vtw, out);
}

// Round 11
// 115.127 us; speedup vs baseline: 2.2545x; 1.0423x over previous
//
#include <hip/hip_runtime.h>

typedef __bf16 bf16x8 __attribute__((ext_vector_type(8)));
typedef __bf16 bf16x4 __attribute__((ext_vector_type(4)));
typedef __bf16 bf16x2 __attribute__((ext_vector_type(2)));
typedef float  f32x4  __attribute__((ext_vector_type(4)));
typedef float  f32x16 __attribute__((ext_vector_type(16)));
typedef int    i32x4  __attribute__((ext_vector_type(4)));

#define MFMA16 __builtin_amdgcn_mfma_f32_16x16x32_bf16
#define MFMA32 __builtin_amdgcn_mfma_f32_32x32x16_bf16

static constexpr int BATCH = 4;
static constexpr int SEQ   = 4096;
static constexpr int CDIM  = 128;
static constexpr int HDIM  = 64;
static constexpr float FIXMAX = 16.0f;   // log2-domain safe upper bound for scores

union FB2  { bf16x2 h; int i; };
union I4B8 { i32x4 i; bf16x8 b; };

// Load 8 contiguous fp32 and convert to bf16x8
__device__ inline bf16x8 load8f_cvt(const float* __restrict__ p) {
    f32x4 a = *reinterpret_cast<const f32x4*>(p);
    f32x4 b = *reinterpret_cast<const f32x4*>(p + 4);
    bf16x8 r;
    r[0] = (__bf16)a[0]; r[1] = (__bf16)a[1]; r[2] = (__bf16)a[2]; r[3] = (__bf16)a[3];
    r[4] = (__bf16)b[0]; r[5] = (__bf16)b[1]; r[6] = (__bf16)b[2]; r[7] = (__bf16)b[3];
    return r;
}

// ---------------------------------------------------------------------------
// Fragment-swizzled layouts (elements, bf16):
//   Q/K: Xswz[(KT*4 + kc)*512 + (h*32 + row)*8 + j] = X[KT*32+row][kc*16 + h*8 + j]
//   V:   Vswz[(KT*8 + ct*2 + kc2)*512 + (h*32 + c_local)*8 + j]
//          = V^T[ct*32+c_local][KT*32 + kc2*16 + h*8 + j]
// A wave's MFMA A/B fragment for a chunk is the contiguous 1KB at lane*16.
// ---------------------------------------------------------------------------

// ---------------------------------------------------------------------------
// Fused projections, 1024 blocks (unchanged — verified).
// ---------------------------------------------------------------------------
__global__ __launch_bounds__(256) void proj_all_kernel(
    const float* __restrict__ x, const float* __restrict__ y,
    const float* __restrict__ Wq, const float* __restrict__ Wk,
    const float* __restrict__ Wv,
    __bf16* __restrict__ Qw, __bf16* __restrict__ Kw, __bf16* __restrict__ Vtw,
    float qscale)
{
    __shared__ __bf16 Wt[64][136];    // transposed weight slice: Wt[cout][cin]
    __shared__ __bf16 Vtile[64][72];  // V transpose tile [c_local][key_local]

    const int job = blockIdx.x >> 8;
    const int bx  = blockIdx.x & 255;
    const int t    = threadIdx.x;
    const int lane = t & 63;
    const int w    = t >> 6;
    const int m    = lane & 15;
    const int quad = lane >> 4;

    if (job <= 1) {
        const float* X    = job ? y  : x;
        const float* W    = job ? Wk : Wq;
        __bf16*      outp = job ? Kw : Qw;
        const float scale = job ? 1.0f : qscale;

        #pragma unroll
        for (int pass = 0; pass < 4; ++pass) {
            int flat = pass * 2048 + t * 8;
            int cin  = flat >> 6;
            int h0   = flat & 63;
            bf16x8 v = load8f_cvt(W + flat);
            #pragma unroll
            for (int j = 0; j < 8; ++j) Wt[h0 + j][cin] = v[j];
        }
        __syncthreads();

        const int row0 = bx * 64 + w * 16;
        bf16x8 af[4];
        #pragma unroll
        for (int kc = 0; kc < 4; ++kc)
            af[kc] = load8f_cvt(X + (long)(row0 + m) * 128 + kc * 32 + quad * 8);

        #pragma unroll
        for (int tn = 0; tn < 4; ++tn) {
            f32x4 acc = {0.f, 0.f, 0.f, 0.f};
            #pragma unroll
            for (int kc = 0; kc < 4; ++kc) {
                bf16x8 bfrag = *reinterpret_cast<const bf16x8*>(&Wt[tn * 16 + m][kc * 32 + quad * 8]);
                acc = MFMA16(af[kc], bfrag, acc, 0, 0, 0);
            }
            #pragma unroll
            for (int r = 0; r < 4; ++r) {
                int  kg   = row0 + quad * 4 + r;   // global row (incl. batch)
                long addr = ((long)(kg >> 5) * 4 + tn) * 512
                          + ((m >> 3) * 32 + (kg & 31)) * 8 + (m & 7);
                outp[addr] = (__bf16)(acc[r] * scale);
            }
        }
    } else {
        const int cob = (job - 2) * 64;   // cout base
        const int ct0 = (job - 2) * 2;    // 32-col group base

        // stage Wv[:, cob..cob+63] transposed
        #pragma unroll
        for (int pass = 0; pass < 4; ++pass) {
            int flat = pass * 2048 + t * 8;
            int cin  = flat >> 6;
            int co0  = flat & 63;
            bf16x8 v = load8f_cvt(Wv + cin * 128 + cob + co0);
            #pragma unroll
            for (int j = 0; j < 8; ++j) Wt[co0 + j][cin] = v[j];
        }
        __syncthreads();

        const int row0 = bx * 64 + w * 16;   // key rows
        bf16x8 af[4];
        #pragma unroll
        for (int kc = 0; kc < 4; ++kc)
            af[kc] = load8f_cvt(y + (long)(row0 + m) * 128 + kc * 32 + quad * 8);

        #pragma unroll
        for (int tn = 0; tn < 4; ++tn) {
            f32x4 acc = {0.f, 0.f, 0.f, 0.f};
            #pragma unroll
            for (int kc = 0; kc < 4; ++kc) {
                bf16x8 bfrag = *reinterpret_cast<const bf16x8*>(&Wt[tn * 16 + m][kc * 32 + quad * 8]);
                acc = MFMA16(af[kc], bfrag, acc, 0, 0, 0);
            }
            bf16x4 pk;
            #pragma unroll
            for (int r = 0; r < 4; ++r) pk[r] = (__bf16)acc[r];
            *reinterpret_cast<bf16x4*>(&Vtile[tn * 16 + m][w * 16 + quad * 4]) = pk;
        }
        __syncthreads();

        // fragment-ordered coalesced store of the 64key x 64c tile
        #pragma unroll
        for (int pp = 0; pp < 2; ++pp) {
            int i       = pp * 256 + t;
            int c_local = i & 31;
            int hh      = (i >> 5) & 1;
            int kc2     = (i >> 6) & 1;
            int ct_l    = (i >> 7) & 1;
            int kt_l    = i >> 8;
            bf16x8 v = *reinterpret_cast<const bf16x8*>(
                &Vtile[ct_l * 32 + c_local][kt_l * 32 + kc2 * 16 + hh * 8]);
            long dst = ((long)(bx * 2 + kt_l) * 8 + (ct0 + ct_l) * 2 + kc2) * 512
                     + (hh * 32 + c_local) * 8;
            *reinterpret_cast<bf16x8*>(Vtw + dst) = v;
        }
    }
}

// ---------------------------------------------------------------------------
// Softmax + in-register P transpose + PV for one 32-row q-subtile.
// ---------------------------------------------------------------------------
__device__ __forceinline__ void softmax_pv(
    const f32x16& s, const bf16x8 (&vf)[4], f32x16& o0, f32x16& o1,
    float& l, int h)
{
    int Dw[8];
    #pragma unroll
    for (int r2 = 0; r2 < 8; ++r2) {
        float p0 = __builtin_amdgcn_exp2f(s[2 * r2]);
        float p1 = __builtin_amdgcn_exp2f(s[2 * r2 + 1]);
        l += p0 + p1;
        FB2 u; u.h[0] = (__bf16)p0; u.h[1] = (__bf16)p1;
        Dw[r2] = u.i;
    }
    #pragma unroll
    for (int kc2 = 0; kc2 < 2; ++kc2) {
        int a0 = Dw[4 * kc2 + 0], a1 = Dw[4 * kc2 + 1];
        int a2 = Dw[4 * kc2 + 2], a3 = Dw[4 * kc2 + 3];
        int r0 = __shfl_xor(a0, 32, 64);
        int r1 = __shfl_xor(a1, 32, 64);
        int r2 = __shfl_xor(a2, 32, 64);
        int r3 = __shfl_xor(a3, 32, 64);
        I4B8 pb;
        pb.i[0] = h ? r2 : a0;
        pb.i[1] = h ? r3 : a1;
        pb.i[2] = h ? a2 : r0;
        pb.i[3] = h ? a3 : r1;
        o0 = MFMA32(vf[0 * 2 + kc2], pb.b, o0, 0, 0, 0);
        o1 = MFMA32(vf[1 * 2 + kc2], pb.b, o1, 0, 0, 0);
    }
}

// ---------------------------------------------------------------------------
// One flash step: 64 q-rows (2 subtiles sharing K/V frags) x 32 keys.
// ---------------------------------------------------------------------------
__device__ __forceinline__ void attn_step(
    const bf16x8 (&kf)[4], const bf16x8 (&vf)[4], const bf16x8 (&qf)[2][4],
    f32x16 (&o_acc)[4], float (&l)[2], int h)
{
    f32x16 s0, s1;
    #pragma unroll
    for (int i = 0; i < 16; ++i) { s0[i] = -FIXMAX; s1[i] = -FIXMAX; }
    #pragma unroll
    for (int kc = 0; kc < 4; ++kc) {
        s0 = MFMA32(kf[kc], qf[0][kc], s0, 0, 0, 0);
        s1 = MFMA32(kf[kc], qf[1][kc], s1, 0, 0, 0);
    }
    softmax_pv(s0, vf, o_acc[0], o_acc[1], l[0], h);
    softmax_pv(s1, vf, o_acc[2], o_acc[3], l[1], h);
}

// ---------------------------------------------------------------------------
// Flash attention, M=64 per wave to halve issued bytes per MFMA.
// Grid 256 = 4 batches x 64 q-tiles (64 rows) = 1 block/CU. Block = 512 thr
// = 8 waves = 4 key-groups x 2 c-halves; 2 waves/SIMD (launch_bounds (512,2):
// live set ~224 regs incl. 64 AGPR acc — fits, no spill). Each wave: 64
// q-rows x 64 channels x 1024 keys, 32 iters x 32 keys; K/V frags register-
// double-buffered one iter ahead. Fixed-max softmax; in-register P transpose;
// 2-round LDS merge epilogue over key-groups.
// ---------------------------------------------------------------------------
__global__ __launch_bounds__(512, 2) void attn_kernel(
    const __bf16* __restrict__ Qs, const __bf16* __restrict__ Ks,
    const __bf16* __restrict__ Vs, float* __restrict__ out)
{
    __shared__ float mbuf[2][2][2][64][33];  // [st][ch][slot][lane][32 o + l]

    const int t    = threadIdx.x;
    const int lane = t & 63;
    const int w    = t >> 6;       // 0..7
    const int ch   = w & 1;        // c-half: channels [ch*64, ch*64+64)
    const int g    = w >> 1;       // key-group 0..3 (keys [g*1024, +1024))
    const int qc   = lane & 31;    // q column
    const int h    = lane >> 5;

    const int bx  = blockIdx.x;
    const int n   = bx >> 6;       // batch
    const int qtl = bx & 63;       // 64-row q-tile within batch

    // Q B-frags for both 32-row subtiles
    bf16x8 qf[2][4];
    #pragma unroll
    for (int st = 0; st < 2; ++st) {
        const long QT = (long)n * 128 + qtl * 2 + st;
        #pragma unroll
        for (int kc = 0; kc < 4; ++kc)
            qf[st][kc] = *reinterpret_cast<const bf16x8*>(Qs + (QT * 4 + kc) * 512 + lane * 8);
    }

    // key stream bases (KT = n*128 + g*32 + kt)
    const __bf16* kb = Ks + ((long)n * 128 + g * 32) * 2048 + lane * 8;
    const __bf16* vb = Vs + ((long)n * 128 + g * 32) * 4096 + (long)ch * 2048 + lane * 8;

    f32x16 o_acc[4];   // [st*2 + ctl]
    #pragma unroll
    for (int a = 0; a < 4; ++a)
        #pragma unroll
        for (int i = 0; i < 16; ++i) o_acc[a][i] = 0.f;
    float l[2] = {0.f, 0.f};

    bf16x8 kfA[4], vfA[4], kfB[4], vfB[4];

    // prologue: iter 0 into A
    #pragma unroll
    for (int kc = 0; kc < 4; ++kc)
        kfA[kc] = *reinterpret_cast<const bf16x8*>(kb + kc * 512);
    #pragma unroll
    for (int j = 0; j < 4; ++j)
        vfA[j] = *reinterpret_cast<const bf16x8*>(vb + j * 512);

    for (int kt = 0; kt < 32; kt += 2) {
        // load kt+1 into B (kt+1 <= 31 always)
        {
            const __bf16* kp = kb + (long)(kt + 1) * 2048;
            const __bf16* vp = vb + (long)(kt + 1) * 4096;
            #pragma unroll
            for (int kc = 0; kc < 4; ++kc)
                kfB[kc] = *reinterpret_cast<const bf16x8*>(kp + kc * 512);
            #pragma unroll
            for (int j = 0; j < 4; ++j)
                vfB[j] = *reinterpret_cast<const bf16x8*>(vp + j * 512);
        }
        attn_step(kfA, vfA, qf, o_acc, l, h);

        // load kt+2 into A
        if (kt < 30) {
            const __bf16* kp = kb + (long)(kt + 2) * 2048;
            const __bf16* vp = vb + (long)(kt + 2) * 4096;
            #pragma unroll
            for (int kc = 0; kc < 4; ++kc)
                kfA[kc] = *reinterpret_cast<const bf16x8*>(kp + kc * 512);
            #pragma unroll
            for (int j = 0; j < 4; ++j)
                vfA[j] = *reinterpret_cast<const bf16x8*>(vp + j * 512);
        }
        attn_step(kfB, vfB, qf, o_acc, l, h);
    }

    // ---- 2-round LDS merge tree over the 4 key-groups per (st, ch) ----
    // Round 1: g=2,3 -> slots 0,1
    if (g >= 2) {
        #pragma unroll
        for (int st = 0; st < 2; ++st) {
            float* dst = &mbuf[st][ch][g - 2][lane][0];
            #pragma unroll
            for (int ctl = 0; ctl < 2; ++ctl)
                #pragma unroll
                for (int i = 0; i < 16; ++i) dst[ctl * 16 + i] = o_acc[st * 2 + ctl][i];
            dst[32] = l[st];
        }
    }
    __syncthreads();
    if (g < 2) {
        #pragma unroll
        for (int st = 0; st < 2; ++st) {
            const float* src = &mbuf[st][ch][g][lane][0];
            #pragma unroll
            for (int ctl = 0; ctl < 2; ++ctl)
                #pragma unroll
                for (int i = 0; i < 16; ++i) o_acc[st * 2 + ctl][i] += src[ctl * 16 + i];
            l[st] += src[32];
        }
    }
    __syncthreads();
    // Round 2: g=1 -> slot 0
    if (g == 1) {
        #pragma unroll
        for (int st = 0; st < 2; ++st) {
            float* dst = &mbuf[st][ch][0][lane][0];
            #pragma unroll
            for (int ctl = 0; ctl < 2; ++ctl)
                #pragma unroll
                for (int i = 0; i < 16; ++i) dst[ctl * 16 + i] = o_acc[st * 2 + ctl][i];
            dst[32] = l[st];
        }
    }
    __syncthreads();

    if (g == 0) {
        #pragma unroll
        for (int st = 0; st < 2; ++st) {
            const float* src = &mbuf[st][ch][0][lane][0];
            #pragma unroll
            for (int ctl = 0; ctl < 2; ++ctl)
                #pragma unroll
                for (int i = 0; i < 16; ++i) o_acc[st * 2 + ctl][i] += src[ctl * 16 + i];
            float lr = l[st] + src[32];
            lr += __shfl_xor(lr, 32, 64);     // cross-half key sum
            const float inv = 1.0f / lr;
            const long row = (long)n * SEQ + qtl * 64 + st * 32 + qc;
            #pragma unroll
            for (int ctl = 0; ctl < 2; ++ctl)
                #pragma unroll
                for (int rg = 0; rg < 4; ++rg) {
                    f32x4 o;
                    #pragma unroll
                    for (int i = 0; i < 4; ++i) o[i] = o_acc[st * 2 + ctl][rg * 4 + i] * inv;
                    *reinterpret_cast<f32x4*>(
                        out + row * CDIM + ch * 64 + ctl * 32 + rg * 8 + h * 4) = o;
                }
        }
    }
}

// ---------------------------------------------------------------------------
extern "C" void kernel_launch(void* const* d_in, const int* in_sizes, int n_in,
                              void* d_out, int out_size, void* d_ws, size_t ws_size,
                              hipStream_t stream)
{
    const float* x  = (const float*)d_in[0];  // [4,4096,128] fp32
    const float* y  = (const float*)d_in[1];  // [4,4096,128] fp32
    const float* Wq = (const float*)d_in[2];  // [128,64]     fp32
    const float* Wk = (const float*)d_in[3];  // [128,64]     fp32
    const float* Wv = (const float*)d_in[4];  // [128,128]    fp32
    float* out = (float*)d_out;               // [4,4096,128] fp32

    __bf16* Qw  = (__bf16*)d_ws;                         // swizzled Q, 2 MB
    __bf16* Kw  = Qw + (long)BATCH * SEQ * HDIM;         // swizzled K, 2 MB
    __bf16* Vtw = Kw + (long)BATCH * SEQ * HDIM;         // swizzled V^T, 4 MB

    // scale = H^-0.5 * log2(e), folded into Q before bf16 rounding
    const float qscale = 0.125f * 1.4426950408889634f;

    proj_all_kernel<<<dim3(1024), dim3(256), 0, stream>>>(
        x, y, Wq, Wk, Wv, Qw, Kw, Vtw, qscale);

    attn_kernel<<<dim3(256), dim3(512), 0, stream>>>(Qw, Kw, Vtw, out);
}

// Round 12
// 108.162 us; speedup vs baseline: 2.3997x; 1.0644x over previous
//
#include <hip/hip_runtime.h>

typedef __bf16 bf16x8 __attribute__((ext_vector_type(8)));
typedef __bf16 bf16x4 __attribute__((ext_vector_type(4)));
typedef __bf16 bf16x2 __attribute__((ext_vector_type(2)));
typedef float  f32x4  __attribute__((ext_vector_type(4)));
typedef float  f32x16 __attribute__((ext_vector_type(16)));
typedef int    i32x4  __attribute__((ext_vector_type(4)));

#define MFMA16 __builtin_amdgcn_mfma_f32_16x16x32_bf16
#define MFMA32 __builtin_amdgcn_mfma_f32_32x32x16_bf16

static constexpr int BATCH = 4;
static constexpr int SEQ   = 4096;
static constexpr int CDIM  = 128;
static constexpr int HDIM  = 64;
static constexpr float FIXMAX = 16.0f;   // log2-domain safe upper bound for scores

union FB2  { bf16x2 h; int i; };
union I4B8 { i32x4 i; bf16x8 b; };

// Load 8 contiguous fp32 and convert to bf16x8
__device__ inline bf16x8 load8f_cvt(const float* __restrict__ p) {
    f32x4 a = *reinterpret_cast<const f32x4*>(p);
    f32x4 b = *reinterpret_cast<const f32x4*>(p + 4);
    bf16x8 r;
    r[0] = (__bf16)a[0]; r[1] = (__bf16)a[1]; r[2] = (__bf16)a[2]; r[3] = (__bf16)a[3];
    r[4] = (__bf16)b[0]; r[5] = (__bf16)b[1]; r[6] = (__bf16)b[2]; r[7] = (__bf16)b[3];
    return r;
}

// ---------------------------------------------------------------------------
// Fragment-swizzled layouts (elements, bf16):
//   Q/K: Xswz[(KT*4 + kc)*512 + (h*32 + row)*8 + j] = X[KT*32+row][kc*16 + h*8 + j]
//   V:   Vswz[(KT*8 + ct*2 + kc2)*512 + (h*32 + c_local)*8 + j]
//          = V^T[ct*32+c_local][KT*32 + kc2*16 + h*8 + j]
// A wave's MFMA A/B fragment for a chunk is the contiguous 1KB at lane*16.
// ---------------------------------------------------------------------------

// ---------------------------------------------------------------------------
// Fused projections, 1024 blocks (unchanged — verified).
// ---------------------------------------------------------------------------
__global__ __launch_bounds__(256) void proj_all_kernel(
    const float* __restrict__ x, const float* __restrict__ y,
    const float* __restrict__ Wq, const float* __restrict__ Wk,
    const float* __restrict__ Wv,
    __bf16* __restrict__ Qw, __bf16* __restrict__ Kw, __bf16* __restrict__ Vtw,
    float qscale)
{
    __shared__ __bf16 Wt[64][136];    // transposed weight slice: Wt[cout][cin]
    __shared__ __bf16 Vtile[64][72];  // V transpose tile [c_local][key_local]

    const int job = blockIdx.x >> 8;
    const int bx  = blockIdx.x & 255;
    const int t    = threadIdx.x;
    const int lane = t & 63;
    const int w    = t >> 6;
    const int m    = lane & 15;
    const int quad = lane >> 4;

    if (job <= 1) {
        const float* X    = job ? y  : x;
        const float* W    = job ? Wk : Wq;
        __bf16*      outp = job ? Kw : Qw;
        const float scale = job ? 1.0f : qscale;

        #pragma unroll
        for (int pass = 0; pass < 4; ++pass) {
            int flat = pass * 2048 + t * 8;
            int cin  = flat >> 6;
            int h0   = flat & 63;
            bf16x8 v = load8f_cvt(W + flat);
            #pragma unroll
            for (int j = 0; j < 8; ++j) Wt[h0 + j][cin] = v[j];
        }
        __syncthreads();

        const int row0 = bx * 64 + w * 16;
        bf16x8 af[4];
        #pragma unroll
        for (int kc = 0; kc < 4; ++kc)
            af[kc] = load8f_cvt(X + (long)(row0 + m) * 128 + kc * 32 + quad * 8);

        #pragma unroll
        for (int tn = 0; tn < 4; ++tn) {
            f32x4 acc = {0.f, 0.f, 0.f, 0.f};
            #pragma unroll
            for (int kc = 0; kc < 4; ++kc) {
                bf16x8 bfrag = *reinterpret_cast<const bf16x8*>(&Wt[tn * 16 + m][kc * 32 + quad * 8]);
                acc = MFMA16(af[kc], bfrag, acc, 0, 0, 0);
            }
            #pragma unroll
            for (int r = 0; r < 4; ++r) {
                int  kg   = row0 + quad * 4 + r;   // global row (incl. batch)
                long addr = ((long)(kg >> 5) * 4 + tn) * 512
                          + ((m >> 3) * 32 + (kg & 31)) * 8 + (m & 7);
                outp[addr] = (__bf16)(acc[r] * scale);
            }
        }
    } else {
        const int cob = (job - 2) * 64;   // cout base
        const int ct0 = (job - 2) * 2;    // 32-col group base

        // stage Wv[:, cob..cob+63] transposed
        #pragma unroll
        for (int pass = 0; pass < 4; ++pass) {
            int flat = pass * 2048 + t * 8;
            int cin  = flat >> 6;
            int co0  = flat & 63;
            bf16x8 v = load8f_cvt(Wv + cin * 128 + cob + co0);
            #pragma unroll
            for (int j = 0; j < 8; ++j) Wt[co0 + j][cin] = v[j];
        }
        __syncthreads();

        const int row0 = bx * 64 + w * 16;   // key rows
        bf16x8 af[4];
        #pragma unroll
        for (int kc = 0; kc < 4; ++kc)
            af[kc] = load8f_cvt(y + (long)(row0 + m) * 128 + kc * 32 + quad * 8);

        #pragma unroll
        for (int tn = 0; tn < 4; ++tn) {
            f32x4 acc = {0.f, 0.f, 0.f, 0.f};
            #pragma unroll
            for (int kc = 0; kc < 4; ++kc) {
                bf16x8 bfrag = *reinterpret_cast<const bf16x8*>(&Wt[tn * 16 + m][kc * 32 + quad * 8]);
                acc = MFMA16(af[kc], bfrag, acc, 0, 0, 0);
            }
            bf16x4 pk;
            #pragma unroll
            for (int r = 0; r < 4; ++r) pk[r] = (__bf16)acc[r];
            *reinterpret_cast<bf16x4*>(&Vtile[tn * 16 + m][w * 16 + quad * 4]) = pk;
        }
        __syncthreads();

        // fragment-ordered coalesced store of the 64key x 64c tile
        #pragma unroll
        for (int pp = 0; pp < 2; ++pp) {
            int i       = pp * 256 + t;
            int c_local = i & 31;
            int hh      = (i >> 5) & 1;
            int kc2     = (i >> 6) & 1;
            int ct_l    = (i >> 7) & 1;
            int kt_l    = i >> 8;
            bf16x8 v = *reinterpret_cast<const bf16x8*>(
                &Vtile[ct_l * 32 + c_local][kt_l * 32 + kc2 * 16 + hh * 8]);
            long dst = ((long)(bx * 2 + kt_l) * 8 + (ct0 + ct_l) * 2 + kc2) * 512
                     + (hh * 32 + c_local) * 8;
            *reinterpret_cast<bf16x8*>(Vtw + dst) = v;
        }
    }
}

// ---------------------------------------------------------------------------
// Flash attention: 1x softmax per (q,k) — wave owns 32 q-rows x ALL 128
// channels x 1024 keys. Block = 512 thr = 8 waves = 4 key-groups x 2
// q-subtiles (wave pairs with same g share K and V streams -> L1 reuse).
// Grid 256 = 1 block/CU; launch_bounds (512,2): live set ~180 regs incl. 64
// AGPR acc fits without spill. K frags double-buffered; V frags loaded
// between S-MFMA issue and softmax (exp2 chain covers L2 latency).
// Fixed-max softmax; in-register P transpose; 2-round LDS merge epilogue.
// ---------------------------------------------------------------------------
__global__ __launch_bounds__(512, 2) void attn_kernel(
    const __bf16* __restrict__ Qs, const __bf16* __restrict__ Ks,
    const __bf16* __restrict__ Vs, float* __restrict__ out)
{
    __shared__ float mbuf[2][2][64][65];  // [qs][slot][lane][64 o + l]

    const int t    = threadIdx.x;
    const int lane = t & 63;
    const int w    = t >> 6;       // 0..7
    const int qs   = w & 1;        // q-subtile (32 rows)
    const int g    = w >> 1;       // key-group 0..3 (keys [g*1024, +1024))
    const int qc   = lane & 31;    // q column
    const int h    = lane >> 5;

    const int bx  = blockIdx.x;
    const int n   = bx >> 6;       // batch
    const int qtl = bx & 63;       // 64-row q-tile within batch

    // Q B-frags: contiguous 1KB per chunk
    const long QT = (long)n * 128 + qtl * 2 + qs;
    bf16x8 qf[4];
    #pragma unroll
    for (int kc = 0; kc < 4; ++kc)
        qf[kc] = *reinterpret_cast<const bf16x8*>(Qs + (QT * 4 + kc) * 512 + lane * 8);

    // key stream bases (KT = n*128 + g*32 + kt)
    const __bf16* kb = Ks + ((long)n * 128 + g * 32) * 2048 + lane * 8;
    const __bf16* vb = Vs + ((long)n * 128 + g * 32) * 4096 + lane * 8;

    f32x16 o_acc[4];   // channels ct*32
    #pragma unroll
    for (int a = 0; a < 4; ++a)
        #pragma unroll
        for (int i = 0; i < 16; ++i) o_acc[a][i] = 0.f;
    float l_a = 0.f, l_b = 0.f;

    bf16x8 kf0[4], kf1[4];

    // prologue: K frags for iter 0
    #pragma unroll
    for (int kc = 0; kc < 4; ++kc)
        kf0[kc] = *reinterpret_cast<const bf16x8*>(kb + kc * 512);

    for (int kt = 0; kt < 32; ++kt) {
        const bf16x8 (&kf)[4] = (kt & 1) ? kf1 : kf0;
        bf16x8 (&kfn)[4]      = (kt & 1) ? kf0 : kf1;

        // S^T = K.Q^T, pre-shifted by -FIXMAX via accumulator init
        f32x16 s;
        #pragma unroll
        for (int i = 0; i < 16; ++i) s[i] = -FIXMAX;
        #pragma unroll
        for (int kc = 0; kc < 4; ++kc)
            s = MFMA32(kf[kc], qf[kc], s, 0, 0, 0);

        // V frags for THIS iter (L2 latency hidden under the exp2 chain below)
        bf16x8 vf[8];
        {
            const __bf16* vp = vb + (long)kt * 4096;
            #pragma unroll
            for (int c = 0; c < 8; ++c)
                vf[c] = *reinterpret_cast<const bf16x8*>(vp + c * 512);
        }
        // K frags for NEXT iter
        if (kt < 31) {
            const __bf16* kp = kb + (long)(kt + 1) * 2048;
            #pragma unroll
            for (int kc = 0; kc < 4; ++kc)
                kfn[kc] = *reinterpret_cast<const bf16x8*>(kp + kc * 512);
        }

        // fixed-max softmax: p = exp2(s - FIXMAX); pack bf16 pairs
        int Dw[8];
        #pragma unroll
        for (int r2 = 0; r2 < 8; ++r2) {
            float p0 = __builtin_amdgcn_exp2f(s[2 * r2]);
            float p1 = __builtin_amdgcn_exp2f(s[2 * r2 + 1]);
            l_a += p0; l_b += p1;
            FB2 u; u.h[0] = (__bf16)p0; u.h[1] = (__bf16)p1;
            Dw[r2] = u.i;
        }

        // C-layout -> B-layout in-register; PV over all 128 channels
        #pragma unroll
        for (int kc2 = 0; kc2 < 2; ++kc2) {
            int a0 = Dw[4 * kc2 + 0], a1 = Dw[4 * kc2 + 1];
            int a2 = Dw[4 * kc2 + 2], a3 = Dw[4 * kc2 + 3];
            int r0 = __shfl_xor(a0, 32, 64);
            int r1 = __shfl_xor(a1, 32, 64);
            int r2 = __shfl_xor(a2, 32, 64);
            int r3 = __shfl_xor(a3, 32, 64);
            I4B8 pb;
            pb.i[0] = h ? r2 : a0;
            pb.i[1] = h ? r3 : a1;
            pb.i[2] = h ? a2 : r0;
            pb.i[3] = h ? a3 : r1;
            #pragma unroll
            for (int ct = 0; ct < 4; ++ct)
                o_acc[ct] = MFMA32(vf[ct * 2 + kc2], pb.b, o_acc[ct], 0, 0, 0);
        }
    }

    float l_run = l_a + l_b;

    // ---- 2-round LDS merge tree over the 4 key-groups per q-subtile ----
    // Round 1: g=2,3 -> slots 0,1
    if (g >= 2) {
        float* dst = &mbuf[qs][g - 2][lane][0];
        #pragma unroll
        for (int ct = 0; ct < 4; ++ct)
            #pragma unroll
            for (int i = 0; i < 16; ++i) dst[ct * 16 + i] = o_acc[ct][i];
        dst[64] = l_run;
    }
    __syncthreads();
    if (g < 2) {
        const float* src = &mbuf[qs][g][lane][0];
        #pragma unroll
        for (int ct = 0; ct < 4; ++ct)
            #pragma unroll
            for (int i = 0; i < 16; ++i) o_acc[ct][i] += src[ct * 16 + i];
        l_run += src[64];
    }
    __syncthreads();
    // Round 2: g=1 -> slot 0
    if (g == 1) {
        float* dst = &mbuf[qs][0][lane][0];
        #pragma unroll
        for (int ct = 0; ct < 4; ++ct)
            #pragma unroll
            for (int i = 0; i < 16; ++i) dst[ct * 16 + i] = o_acc[ct][i];
        dst[64] = l_run;
    }
    __syncthreads();

    if (g == 0) {
        const float* src = &mbuf[qs][0][lane][0];
        #pragma unroll
        for (int ct = 0; ct < 4; ++ct)
            #pragma unroll
            for (int i = 0; i < 16; ++i) o_acc[ct][i] += src[ct * 16 + i];
        l_run += src[64];

        l_run += __shfl_xor(l_run, 32, 64);   // cross-half key sum
        const float inv = 1.0f / l_run;
        const long row = (long)n * SEQ + qtl * 64 + qs * 32 + qc;
        #pragma unroll
        for (int ct = 0; ct < 4; ++ct)
            #pragma unroll
            for (int rg = 0; rg < 4; ++rg) {
                f32x4 o;
                #pragma unroll
                for (int i = 0; i < 4; ++i) o[i] = o_acc[ct][rg * 4 + i] * inv;
                *reinterpret_cast<f32x4*>(
                    out + row * CDIM + ct * 32 + rg * 8 + h * 4) = o;
            }
    }
}

// ---------------------------------------------------------------------------
extern "C" void kernel_launch(void* const* d_in, const int* in_sizes, int n_in,
                              void* d_out, int out_size, void* d_ws, size_t ws_size,
                              hipStream_t stream)
{
    const float* x  = (const float*)d_in[0];  // [4,4096,128] fp32
    const float* y  = (const float*)d_in[1];  // [4,4096,128] fp32
    const float* Wq = (const float*)d_in[2];  // [128,64]     fp32
    const float* Wk = (const float*)d_in[3];  // [128,64]     fp32
    const float* Wv = (const float*)d_in[4];  // [128,128]    fp32
    float* out = (float*)d_out;               // [4,4096,128] fp32

    __bf16* Qw  = (__bf16*)d_ws;                         // swizzled Q, 2 MB
    __bf16* Kw  = Qw + (long)BATCH * SEQ * HDIM;         // swizzled K, 2 MB
    __bf16* Vtw = Kw + (long)BATCH * SEQ * HDIM;         // swizzled V^T, 4 MB

    // scale = H^-0.5 * log2(e), folded into Q before bf16 rounding
    const float qscale = 0.125f * 1.4426950408889634f;

    proj_all_kernel<<<dim3(1024), dim3(256), 0, stream>>>(
        x, y, Wq, Wk, Wv, Qw, Kw, Vtw, qscale);

    attn_kernel<<<dim3(256), dim3(512), 0, stream>>>(Qw, Kw, Vtw, out);
}